// Round 1
// baseline (792.144 us; speedup 1.0000x reference)
//
#include <hip/hip_runtime.h>
#include <stdint.h>
#include <math.h>

#define T_TOK 2048
#define DIM   2048
#define FDIM  2048
#define NE    8

#define BM 128
#define BN 128
#define BK 32
#define LDB 40   // padded LDS stride (halfwords) for transposed B tiles

typedef unsigned short u16;
typedef short s16x8 __attribute__((ext_vector_type(8)));
typedef float f32x4 __attribute__((ext_vector_type(4)));

__device__ __forceinline__ u16 f2bf(float f) {
    union { float f; unsigned int u; } v; v.f = f;
    unsigned int r = v.u + 0x7FFFu + ((v.u >> 16) & 1u);  // RNE
    return (u16)(r >> 16);
}

// ---------------- router: logits, argmax, sigmoid score, counts ----------------
__global__ __launch_bounds__(256) void router_k(
    const float* __restrict__ x, const float* __restrict__ rw,
    float* __restrict__ score, int* __restrict__ eidx, int* __restrict__ counts)
{
    int t = blockIdx.x;
    int tid = threadIdx.x;
    float p[8] = {0.f,0.f,0.f,0.f,0.f,0.f,0.f,0.f};
    const float* xrow = x + (size_t)t * DIM;
    for (int d = tid; d < DIM; d += 256) {
        float xv = xrow[d];
        const float4* r = (const float4*)(rw + (size_t)d * 8);
        float4 r0 = r[0], r1 = r[1];
        p[0] += xv * r0.x; p[1] += xv * r0.y; p[2] += xv * r0.z; p[3] += xv * r0.w;
        p[4] += xv * r1.x; p[5] += xv * r1.y; p[6] += xv * r1.z; p[7] += xv * r1.w;
    }
    #pragma unroll
    for (int off = 32; off > 0; off >>= 1) {
        #pragma unroll
        for (int e = 0; e < 8; ++e) p[e] += __shfl_down(p[e], off);
    }
    __shared__ float red[4][8];
    int wave = tid >> 6, lane = tid & 63;
    if (lane == 0) {
        #pragma unroll
        for (int e = 0; e < 8; ++e) red[wave][e] = p[e];
    }
    __syncthreads();
    if (tid == 0) {
        float lg[8];
        #pragma unroll
        for (int e = 0; e < 8; ++e) lg[e] = red[0][e] + red[1][e] + red[2][e] + red[3][e];
        int best = 0; float bv = lg[0];
        #pragma unroll
        for (int e = 1; e < 8; ++e) { if (lg[e] > bv) { bv = lg[e]; best = e; } }
        score[t] = 1.f / (1.f + expf(-bv));
        eidx[t] = best;
        atomicAdd(&counts[best], 1);
    }
}

// ---------------- scan: exclusive prefix of counts ----------------
__global__ void scan_k(const int* __restrict__ counts, int* __restrict__ offs,
                       int* __restrict__ fill)
{
    if (threadIdx.x == 0 && blockIdx.x == 0) {
        int run = 0;
        for (int e = 0; e < NE; ++e) { offs[e] = run; fill[e] = run; run += counts[e]; }
    }
}

// ---------------- gather: compact scaled rows (bf16) + raw bf16 rows ----------------
__global__ __launch_bounds__(256) void gather_k(
    const float* __restrict__ x, const float* __restrict__ score,
    const int* __restrict__ eidx, int* __restrict__ fill,
    int* __restrict__ tokmap, u16* __restrict__ xsc, u16* __restrict__ xbf)
{
    int t = blockIdx.x, tid = threadIdx.x;
    __shared__ int sp;
    if (tid == 0) {
        int e = eidx[t];
        int p = atomicAdd(&fill[e], 1);
        tokmap[p] = t;
        sp = p;
    }
    __syncthreads();
    int pos = sp;
    float s = score[t];
    const float4* xr = (const float4*)(x + (size_t)t * DIM);
    float4 a = xr[tid * 2], b = xr[tid * 2 + 1];
    alignas(16) u16 raw[8] = { f2bf(a.x), f2bf(a.y), f2bf(a.z), f2bf(a.w),
                               f2bf(b.x), f2bf(b.y), f2bf(b.z), f2bf(b.w) };
    alignas(16) u16 scl[8] = { f2bf(a.x*s), f2bf(a.y*s), f2bf(a.z*s), f2bf(a.w*s),
                               f2bf(b.x*s), f2bf(b.y*s), f2bf(b.z*s), f2bf(b.w*s) };
    *(s16x8*)(xbf + (size_t)t * DIM + tid * 8)   = *(s16x8*)raw;
    *(s16x8*)(xsc + (size_t)pos * DIM + tid * 8) = *(s16x8*)scl;
}

// stage a 32x128 fp32 [k][n] weight tile, transposed+converted into LDS [n][k]
__device__ __forceinline__ void stageB(const float* __restrict__ W, u16* Bs,
                                       int bn, int bkh)
{
    const float* wp = W + (size_t)bkh * FDIM + bn;
    alignas(16) u16 tmp[16];
    #pragma unroll
    for (int j = 0; j < 16; ++j) tmp[j] = f2bf(wp[(size_t)j * FDIM]);
    *(s16x8*)&Bs[bn * LDB + bkh]     = *(s16x8*)&tmp[0];
    *(s16x8*)&Bs[bn * LDB + bkh + 8] = *(s16x8*)&tmp[8];
}

// ---------------- grouped gate/up GEMM + SiLU*up -> bf16 H ----------------
__global__ __launch_bounds__(256) void gateup_k(
    const u16* __restrict__ xsc, const u16* __restrict__ xbf,
    const float* __restrict__ gate_w, const float* __restrict__ up_w,
    const float* __restrict__ sgw, const float* __restrict__ suw,
    const int* __restrict__ counts, const int* __restrict__ offs,
    u16* __restrict__ Hbf, u16* __restrict__ Hs)
{
    int bid = blockIdx.x;
    int g  = bid >> 8;
    int mt = (bid >> 4) & 15;
    int nt = bid & 15;

    int M; const u16* A; const float* Wg; const float* Wu; u16* Ho;
    if (g < NE) {
        M = counts[g];
        int ro = offs[g];
        A  = xsc + (size_t)ro * DIM;
        Wg = gate_w + (size_t)g * DIM * FDIM;
        Wu = up_w  + (size_t)g * DIM * FDIM;
        Ho = Hbf + (size_t)ro * FDIM;
    } else {
        M = T_TOK; A = xbf; Wg = sgw; Wu = suw; Ho = Hs;
    }
    int m0 = mt * BM;
    if (m0 >= M) return;
    int n0 = nt * BN;

    __shared__ u16 As[BM * BK];
    __shared__ u16 Bg[BN * LDB];
    __shared__ u16 Bu[BN * LDB];

    int tid  = threadIdx.x;
    int lane = tid & 63;
    int wave = tid >> 6;
    int wm = (wave >> 1) * 64;
    int wn = (wave & 1) * 64;

    f32x4 accg[4][4], accu[4][4];
    #pragma unroll
    for (int i = 0; i < 4; ++i)
        #pragma unroll
        for (int j = 0; j < 4; ++j) { accg[i][j] = (f32x4)0.f; accu[i][j] = (f32x4)0.f; }

    // A staging map: 2 passes of 64 rows; thread -> (row, 16B chunk)
    int ar = tid >> 2;
    int ac = (tid & 3) * 8;
    int arow0 = min(m0 + ar,      M - 1);
    int arow1 = min(m0 + 64 + ar, M - 1);

    // B staging map: thread -> (n, k-half)
    int bn  = tid & 127;
    int bkh = (tid >> 7) * 16;

    int am   = wm + (lane & 15);
    int koff = (lane >> 4) * 8;

    for (int k0 = 0; k0 < DIM; k0 += BK) {
        *(s16x8*)&As[ar * BK + ac]        = *(const s16x8*)&A[(size_t)arow0 * DIM + k0 + ac];
        *(s16x8*)&As[(64 + ar) * BK + ac] = *(const s16x8*)&A[(size_t)arow1 * DIM + k0 + ac];
        stageB(Wg + (size_t)k0 * FDIM + n0, Bg, bn, bkh);
        stageB(Wu + (size_t)k0 * FDIM + n0, Bu, bn, bkh);
        __syncthreads();

        s16x8 af[4];
        #pragma unroll
        for (int i = 0; i < 4; ++i)
            af[i] = *(const s16x8*)&As[(am + i * 16) * BK + koff];
        #pragma unroll
        for (int j = 0; j < 4; ++j) {
            int bc = wn + j * 16 + (lane & 15);
            s16x8 bg = *(const s16x8*)&Bg[bc * LDB + koff];
            s16x8 bu = *(const s16x8*)&Bu[bc * LDB + koff];
            #pragma unroll
            for (int i = 0; i < 4; ++i) {
                accg[i][j] = __builtin_amdgcn_mfma_f32_16x16x32_bf16(af[i], bg, accg[i][j], 0, 0, 0);
                accu[i][j] = __builtin_amdgcn_mfma_f32_16x16x32_bf16(af[i], bu, accu[i][j], 0, 0, 0);
            }
        }
        __syncthreads();
    }

    int rbase = wm + ((lane >> 4) << 2);
    int cbase = n0 + wn + (lane & 15);
    #pragma unroll
    for (int i = 0; i < 4; ++i) {
        #pragma unroll
        for (int j = 0; j < 4; ++j) {
            #pragma unroll
            for (int r = 0; r < 4; ++r) {
                int row = m0 + rbase + i * 16 + r;
                if (row < M) {
                    float gv = accg[i][j][r];
                    float uv = accu[i][j][r];
                    float h = gv / (1.f + expf(-gv)) * uv;
                    Ho[(size_t)row * FDIM + cbase + j * 16] = f2bf(h);
                }
            }
        }
    }
}

// ---------------- grouped down GEMM, scatter-add into out ----------------
__global__ __launch_bounds__(256) void down_k(
    const u16* __restrict__ Hbf, const u16* __restrict__ Hs,
    const float* __restrict__ down_w, const float* __restrict__ sdw,
    const int* __restrict__ counts, const int* __restrict__ offs,
    const int* __restrict__ tokmap, float* __restrict__ out)
{
    int bid = blockIdx.x;
    int g  = bid >> 8;
    int mt = (bid >> 4) & 15;
    int nt = bid & 15;

    int M, ro; const u16* A; const float* W;
    if (g < NE) {
        M = counts[g];
        ro = offs[g];
        A = Hbf + (size_t)ro * FDIM;
        W = down_w + (size_t)g * FDIM * DIM;
    } else {
        M = T_TOK; ro = 0; A = Hs; W = sdw;
    }
    int m0 = mt * BM;
    if (m0 >= M) return;
    int n0 = nt * BN;

    __shared__ u16 As[BM * BK];
    __shared__ u16 Bd[BN * LDB];

    int tid  = threadIdx.x;
    int lane = tid & 63;
    int wave = tid >> 6;
    int wm = (wave >> 1) * 64;
    int wn = (wave & 1) * 64;

    f32x4 acc[4][4];
    #pragma unroll
    for (int i = 0; i < 4; ++i)
        #pragma unroll
        for (int j = 0; j < 4; ++j) acc[i][j] = (f32x4)0.f;

    int ar = tid >> 2;
    int ac = (tid & 3) * 8;
    int arow0 = min(m0 + ar,      M - 1);
    int arow1 = min(m0 + 64 + ar, M - 1);
    int bn  = tid & 127;
    int bkh = (tid >> 7) * 16;

    int am   = wm + (lane & 15);
    int koff = (lane >> 4) * 8;

    for (int k0 = 0; k0 < FDIM; k0 += BK) {
        *(s16x8*)&As[ar * BK + ac]        = *(const s16x8*)&A[(size_t)arow0 * FDIM + k0 + ac];
        *(s16x8*)&As[(64 + ar) * BK + ac] = *(const s16x8*)&A[(size_t)arow1 * FDIM + k0 + ac];
        stageB(W + (size_t)k0 * DIM + n0, Bd, bn, bkh);
        __syncthreads();

        s16x8 af[4];
        #pragma unroll
        for (int i = 0; i < 4; ++i)
            af[i] = *(const s16x8*)&As[(am + i * 16) * BK + koff];
        #pragma unroll
        for (int j = 0; j < 4; ++j) {
            int bc = wn + j * 16 + (lane & 15);
            s16x8 bd = *(const s16x8*)&Bd[bc * LDB + koff];
            #pragma unroll
            for (int i = 0; i < 4; ++i)
                acc[i][j] = __builtin_amdgcn_mfma_f32_16x16x32_bf16(af[i], bd, acc[i][j], 0, 0, 0);
        }
        __syncthreads();
    }

    int rbase = wm + ((lane >> 4) << 2);
    int cbase = n0 + wn + (lane & 15);
    #pragma unroll
    for (int i = 0; i < 4; ++i) {
        #pragma unroll
        for (int r = 0; r < 4; ++r) {
            int row = m0 + rbase + i * 16 + r;
            if (row < M) {
                int tok = (g < NE) ? tokmap[ro + row] : row;
                #pragma unroll
                for (int j = 0; j < 4; ++j)
                    atomicAdd(&out[(size_t)tok * DIM + cbase + j * 16], acc[i][j][r]);
            }
        }
    }
}

extern "C" void kernel_launch(void* const* d_in, const int* in_sizes, int n_in,
                              void* d_out, int out_size, void* d_ws, size_t ws_size,
                              hipStream_t stream) {
    const float* x   = (const float*)d_in[0];
    const float* rw  = (const float*)d_in[1];
    const float* gw  = (const float*)d_in[2];
    const float* uw  = (const float*)d_in[3];
    const float* dw  = (const float*)d_in[4];
    const float* sgw = (const float*)d_in[5];
    const float* suw = (const float*)d_in[6];
    const float* sdw = (const float*)d_in[7];
    float* out = (float*)d_out;

    char* ws = (char*)d_ws;
    float* score = (float*)(ws);
    int* eidx    = (int*)(ws + 8192);
    int* counts  = (int*)(ws + 16384);
    int* fill    = (int*)(ws + 16448);
    int* offs    = (int*)(ws + 16512);
    int* tokmap  = (int*)(ws + 16576);
    u16* xsc = (u16*)(ws + 32768);
    u16* xbf = (u16*)(ws + 32768 + 1ull * 8388608);
    u16* Hbf = (u16*)(ws + 32768 + 2ull * 8388608);
    u16* Hs  = (u16*)(ws + 32768 + 3ull * 8388608);

    hipMemsetAsync(counts, 0, 128, stream);                       // counts + fill
    hipMemsetAsync(out, 0, (size_t)out_size * sizeof(float), stream);

    router_k<<<T_TOK, 256, 0, stream>>>(x, rw, score, eidx, counts);
    scan_k<<<1, 64, 0, stream>>>(counts, offs, fill);
    gather_k<<<T_TOK, 256, 0, stream>>>(x, score, eidx, fill, tokmap, xsc, xbf);
    gateup_k<<<NE * 256 + 256, 256, 0, stream>>>(xsc, xbf, gw, uw, sgw, suw,
                                                 counts, offs, Hbf, Hs);
    down_k<<<NE * 256 + 256, 256, 0, stream>>>(Hbf, Hs, dw, sdw,
                                               counts, offs, tokmap, out);
}